// Round 2
// 1395.811 us; speedup vs baseline: 1.3704x; 1.3704x over previous
//
#include <hip/hip_runtime.h>
#include <stdint.h>

// Problem dims (fixed by reference)
#define MB_ 2
#define LL_ 2048
#define M_ (MB_*LL_)   // 4096 tokens
#define H_ 4096
#define I_ 11008

typedef __attribute__((ext_vector_type(8))) short bf16x8;
typedef __attribute__((ext_vector_type(4))) float f32x4;
typedef __attribute__((ext_vector_type(4))) unsigned short us4;

__device__ __forceinline__ unsigned short f2bf(float f) {
  union { float f; unsigned int u; } v; v.f = f;
  unsigned int r = v.u + 0x7FFFu + ((v.u >> 16) & 1u);  // RNE
  return (unsigned short)(r >> 16);
}

__device__ __forceinline__ void gl2lds16(const void* g, void* l) {
  __builtin_amdgcn_global_load_lds(
      (const __attribute__((address_space(1))) void*)g,
      (__attribute__((address_space(3))) void*)l, 16, 0, 0);
}

// counted waits + raw barrier. The volatile asm with "memory" clobber is the
// real scheduling fence; s_barrier alone is not a memory fence for the
// compiler (rule: every raw barrier is preceded by one of these).
#define WAITV4 asm volatile("s_waitcnt vmcnt(4)" ::: "memory")
#define WAITV0 asm volatile("s_waitcnt vmcnt(0)" ::: "memory")
#define BAR    __builtin_amdgcn_s_barrier()

// ---------------------------------------------------------------------------
// Compact active token indices. Single block. idx[0..cnt) = active tokens,
// idx[cnt..M_) = 0 (padding so downstream gathers stay in-bounds).
// ---------------------------------------------------------------------------
__global__ __launch_bounds__(256)
void compact_mask(const int* __restrict__ mask, int* __restrict__ idx,
                  int* __restrict__ cnt) {
  __shared__ int lcnt[256];
  __shared__ int loff[256];
  __shared__ int stot;
  const int t = threadIdx.x;
  const int base = t * 16;
  int c = 0;
#pragma unroll
  for (int j = 0; j < 16; j++) c += (mask[base + j] != 0);
  lcnt[t] = c;
  __syncthreads();
  if (t == 0) {
    int s = 0;
    for (int i = 0; i < 256; i++) { loff[i] = s; s += lcnt[i]; }
    stot = s;
    cnt[0] = s;
  }
  __syncthreads();
  int o = loff[t];
#pragma unroll
  for (int j = 0; j < 16; j++)
    if (mask[base + j] != 0) idx[o++] = base + j;
  const int total = stot;
  for (int s = total + t; s < M_; s += 256) idx[s] = 0;
}

// ---------------------------------------------------------------------------
// fp32 -> bf16 bulk conversion (8 elems / thread)
// ---------------------------------------------------------------------------
__global__ __launch_bounds__(256)
void cvt_bf16(const float* __restrict__ src, unsigned short* __restrict__ dst, int n8) {
  int i = blockIdx.x * blockDim.x + threadIdx.x;
  if (i >= n8) return;
  const float4* s = (const float4*)src + (size_t)i * 2;
  float4 a = s[0], b = s[1];
  us4 lo = { f2bf(a.x), f2bf(a.y), f2bf(a.z), f2bf(a.w) };
  us4 hi = { f2bf(b.x), f2bf(b.y), f2bf(b.z), f2bf(b.w) };
  us4* d = (us4*)dst + (size_t)i * 2;
  d[0] = lo; d[1] = hi;
}

// ---------------------------------------------------------------------------
// Gather active hs rows -> compacted bf16 [slot, H].  grid = (M_, H_/2048)
// ---------------------------------------------------------------------------
__global__ __launch_bounds__(256)
void gather_cvt_hs(const float* __restrict__ hs, const int* __restrict__ idx,
                   unsigned short* __restrict__ dst) {
  const int slot = blockIdx.x;
  const int row  = idx[slot];
  const int col  = (blockIdx.y * 256 + threadIdx.x) * 8;
  const float4* s = (const float4*)(hs + (size_t)row * H_ + col);
  float4 a = s[0], b = s[1];
  us4 lo = { f2bf(a.x), f2bf(a.y), f2bf(a.z), f2bf(a.w) };
  us4 hi = { f2bf(b.x), f2bf(b.y), f2bf(b.z), f2bf(b.w) };
  unsigned short* d = dst + (size_t)slot * H_ + col;
  *(us4*)d = lo;
  *(us4*)(d + 4) = hi;
}

// ---------------------------------------------------------------------------
// GEMM1 compacted: h[slot,i] = up * silu(gate) for active slots.
// 3-buffer 2-deep prefetch pipeline, counted vmcnt, 1 barrier per K-step.
// Tile M=128, N=64 dual (up+gate). XCD-swizzled block mapping.
// ---------------------------------------------------------------------------
__global__ __launch_bounds__(256)
void mlp_upgate3(const unsigned short* __restrict__ hs16c,
                 const unsigned short* __restrict__ wu16,
                 const unsigned short* __restrict__ wg16,
                 const int* __restrict__ cnt,
                 unsigned short* __restrict__ hbuf)
{
  const int mtiles = (cnt[0] + 127) >> 7;

  // bijective XCD swizzle: nwg = 32*172 = 5504, 5504 % 8 == 0, chunk = 688
  const int lin = blockIdx.y * 32 + blockIdx.x;
  const int sw  = (lin & 7) * 688 + (lin >> 3);
  const int mt  = sw & 31;   // m-tile fastest: active m-blocks of one n-tile
  const int nt  = sw >> 5;   // co-reside on one XCD -> weight panel L2-hits
  if (mt >= mtiles) return;

  __shared__ unsigned short As[3][128 * 32];
  __shared__ unsigned short Bu[3][64 * 32];
  __shared__ unsigned short Bg[3][64 * 32];

  const int tid  = threadIdx.x;
  const int m0   = mt * 128;
  const int n0   = nt * 64;
  const int w    = tid >> 6;
  const int lane = tid & 63;
  const int quad = lane >> 4;
  const int rrow = lane & 15;
  const int wm   = (w & 1) * 64;
  const int wn   = (w >> 1) * 32;

  const int lr = lane >> 2;
  const int lc = (lane & 3) * 8;
  const unsigned short* pa0 = hs16c + (size_t)(m0 + w * 32 + lr) * H_ + lc;
  const unsigned short* pa1 = pa0 + (size_t)16 * H_;
  const unsigned short* pu  = wu16 + (size_t)(n0 + w * 16 + lr) * H_ + lc;
  const unsigned short* pg  = wg16 + (size_t)(n0 + w * 16 + lr) * H_ + lc;

  auto stage = [&](int t, int b) {
    const int k0 = t * 32;
    gl2lds16(pa0 + k0, &As[b][(w * 32) * 32]);
    gl2lds16(pa1 + k0, &As[b][(w * 32 + 16) * 32]);
    gl2lds16(pu  + k0, &Bu[b][(w * 16) * 32]);
    gl2lds16(pg  + k0, &Bg[b][(w * 16) * 32]);
  };

  f32x4 accU[4][2], accG[4][2];
  const f32x4 zero = {0.f, 0.f, 0.f, 0.f};
  for (int i = 0; i < 4; i++)
    for (int j = 0; j < 2; j++) { accU[i][j] = zero; accG[i][j] = zero; }

  const int NT = H_ / 32;  // 128
  stage(0, 0);
  stage(1, 1);
  WAITV4;  // tile 0 landed; tile 1's 4 loads stay in flight
  BAR;

  int b = 0, bs = 2;  // current buffer, stage target = (b+2)%3
  for (int t = 0; t < NT; ++t) {
    if (t + 2 < NT) stage(t + 2, bs);  // buf[(t+2)%3] == buf[(t-1)%3]: fully
                                       // consumed before last barrier -> safe
    bf16x8 af[4], bu[2], bg[2];
#pragma unroll
    for (int mi = 0; mi < 4; mi++)
      af[mi] = *(const bf16x8*)&As[b][(wm + mi * 16 + rrow) * 32 + quad * 8];
#pragma unroll
    for (int ni = 0; ni < 2; ni++) {
      bu[ni] = *(const bf16x8*)&Bu[b][(wn + ni * 16 + rrow) * 32 + quad * 8];
      bg[ni] = *(const bf16x8*)&Bg[b][(wn + ni * 16 + rrow) * 32 + quad * 8];
    }
#pragma unroll
    for (int mi = 0; mi < 4; mi++)
#pragma unroll
      for (int ni = 0; ni < 2; ni++) {
        accU[mi][ni] = __builtin_amdgcn_mfma_f32_16x16x32_bf16(af[mi], bu[ni], accU[mi][ni], 0, 0, 0);
        accG[mi][ni] = __builtin_amdgcn_mfma_f32_16x16x32_bf16(af[mi], bg[ni], accG[mi][ni], 0, 0, 0);
      }
    if (t + 2 < NT) { WAITV4; } else { WAITV0; }  // tile t+1 ready; never
    BAR;                                          // drain to 0 mid-loop
    b  = (b  + 1 == 3) ? 0 : b  + 1;
    bs = (bs + 1 == 3) ? 0 : bs + 1;
  }

  // epilogue: C/D layout col=lane&15, row=quad*4+reg (verified m89/m91)
#pragma unroll
  for (int mi = 0; mi < 4; mi++)
#pragma unroll
    for (int ni = 0; ni < 2; ni++)
#pragma unroll
      for (int r = 0; r < 4; r++) {
        int row = wm + mi * 16 + quad * 4 + r;
        int col = wn + ni * 16 + rrow;
        float u = accU[mi][ni][r];
        float g = accG[mi][ni][r];
        float sig = 1.0f / (1.0f + __expf(-g));
        hbuf[(size_t)(m0 + row) * I_ + n0 + col] = f2bf(u * g * sig);
      }
}

// ---------------------------------------------------------------------------
// GEMM2 compacted: out[idx[slot],n] = sum_i h[slot,i]*wd[n,i]. Scatter rows.
// Tile 128x128, BK=32, same 3-buffer counted-vmcnt pipeline.
// ---------------------------------------------------------------------------
__global__ __launch_bounds__(256)
void mlp_down3(const unsigned short* __restrict__ hbuf,
               const unsigned short* __restrict__ wd16,
               const int* __restrict__ idx, const int* __restrict__ cnt,
               float* __restrict__ out)
{
  const int count  = cnt[0];
  const int mtiles = (count + 127) >> 7;

  // bijective XCD swizzle: nwg = 32*32 = 1024, chunk = 128
  const int lin = blockIdx.y * 32 + blockIdx.x;
  const int sw  = (lin & 7) * 128 + (lin >> 3);
  const int mt  = sw & 31;
  const int nt  = sw >> 5;
  if (mt >= mtiles) return;

  __shared__ unsigned short As[3][128 * 32];
  __shared__ unsigned short Bs[3][128 * 32];

  const int tid  = threadIdx.x;
  const int m0   = mt * 128;
  const int n0   = nt * 128;
  const int w    = tid >> 6;
  const int lane = tid & 63;
  const int quad = lane >> 4;
  const int rrow = lane & 15;
  const int wm   = (w & 1) * 64;
  const int wn   = (w >> 1) * 64;

  const int lr = lane >> 2;
  const int lc = (lane & 3) * 8;
  const unsigned short* pa0 = hbuf + (size_t)(m0 + w * 32 + lr) * I_ + lc;
  const unsigned short* pa1 = pa0 + (size_t)16 * I_;
  const unsigned short* pb0 = wd16 + (size_t)(n0 + w * 32 + lr) * I_ + lc;
  const unsigned short* pb1 = pb0 + (size_t)16 * I_;

  auto stage = [&](int t, int b) {
    const int k0 = t * 32;
    gl2lds16(pa0 + k0, &As[b][(w * 32) * 32]);
    gl2lds16(pa1 + k0, &As[b][(w * 32 + 16) * 32]);
    gl2lds16(pb0 + k0, &Bs[b][(w * 32) * 32]);
    gl2lds16(pb1 + k0, &Bs[b][(w * 32 + 16) * 32]);
  };

  f32x4 acc[4][4];
  const f32x4 zero = {0.f, 0.f, 0.f, 0.f};
  for (int i = 0; i < 4; i++)
    for (int j = 0; j < 4; j++) acc[i][j] = zero;

  const int NT = I_ / 32;  // 344
  stage(0, 0);
  stage(1, 1);
  WAITV4;
  BAR;

  int b = 0, bs = 2;
  for (int t = 0; t < NT; ++t) {
    if (t + 2 < NT) stage(t + 2, bs);
    bf16x8 af[4], bf[4];
#pragma unroll
    for (int mi = 0; mi < 4; mi++)
      af[mi] = *(const bf16x8*)&As[b][(wm + mi * 16 + rrow) * 32 + quad * 8];
#pragma unroll
    for (int ni = 0; ni < 4; ni++)
      bf[ni] = *(const bf16x8*)&Bs[b][(wn + ni * 16 + rrow) * 32 + quad * 8];
#pragma unroll
    for (int mi = 0; mi < 4; mi++)
#pragma unroll
      for (int ni = 0; ni < 4; ni++)
        acc[mi][ni] = __builtin_amdgcn_mfma_f32_16x16x32_bf16(af[mi], bf[ni], acc[mi][ni], 0, 0, 0);
    if (t + 2 < NT) { WAITV4; } else { WAITV0; }
    BAR;
    b  = (b  + 1 == 3) ? 0 : b  + 1;
    bs = (bs + 1 == 3) ? 0 : bs + 1;
  }

#pragma unroll
  for (int mi = 0; mi < 4; mi++)
#pragma unroll
    for (int r = 0; r < 4; r++) {
      int row  = wm + mi * 16 + quad * 4 + r;
      int slot = m0 + row;
      if (slot < count) {
        int tok = idx[slot];
        float* orow = out + (size_t)tok * H_ + n0;
#pragma unroll
        for (int ni = 0; ni < 4; ni++)
          orow[wn + ni * 16 + rrow] = acc[mi][ni][r];
      }
    }
}

// ===========================================================================
// Fallback path (round-1 kernels) if ws_size is too small.
// ===========================================================================
#define TM 128
#define TN 128
#define BK 32
#define LDK 40

__global__ __launch_bounds__(256)
void mlp_upgate_fb(const float* __restrict__ hs, const float* __restrict__ wu,
                   const float* __restrict__ wg, const int* __restrict__ mask,
                   unsigned short* __restrict__ hbuf)
{
  __shared__ unsigned short As[TM * LDK];
  __shared__ unsigned short Bu[TN * LDK];
  __shared__ unsigned short Bg[TN * LDK];
  __shared__ float smask[TM];

  const int tid = threadIdx.x;
  const int m0 = blockIdx.x * TM;
  const int n0 = blockIdx.y * TN;
  if (tid < TM) smask[tid] = (float)mask[m0 + tid];
  const int wave = tid >> 6, lane = tid & 63;
  const int quad = lane >> 4, rrow = lane & 15;
  const int wm = (wave & 1) * 64, wn = (wave >> 1) * 64;

  f32x4 accU[4][4], accG[4][4];
  const f32x4 zero = {0.f, 0.f, 0.f, 0.f};
  for (int i = 0; i < 4; i++)
    for (int j = 0; j < 4; j++) { accU[i][j] = zero; accG[i][j] = zero; }

  for (int k0 = 0; k0 < H_; k0 += BK) {
#pragma unroll
    for (int s = 0; s < 4; s++) {
      int idx2 = tid + s * 256, row = idx2 >> 3, c4 = (idx2 & 7) * 4;
      float4 a = *(const float4*)&hs[(size_t)(m0 + row) * H_ + k0 + c4];
      float4 u = *(const float4*)&wu[(size_t)(n0 + row) * H_ + k0 + c4];
      float4 g = *(const float4*)&wg[(size_t)(n0 + row) * H_ + k0 + c4];
      us4 av = { f2bf(a.x), f2bf(a.y), f2bf(a.z), f2bf(a.w) };
      us4 uv = { f2bf(u.x), f2bf(u.y), f2bf(u.z), f2bf(u.w) };
      us4 gv = { f2bf(g.x), f2bf(g.y), f2bf(g.z), f2bf(g.w) };
      *(us4*)&As[row * LDK + c4] = av;
      *(us4*)&Bu[row * LDK + c4] = uv;
      *(us4*)&Bg[row * LDK + c4] = gv;
    }
    __syncthreads();
    bf16x8 af[4], bu[4], bg[4];
#pragma unroll
    for (int mi = 0; mi < 4; mi++)
      af[mi] = *(const bf16x8*)&As[(wm + mi * 16 + rrow) * LDK + quad * 8];
#pragma unroll
    for (int ni = 0; ni < 4; ni++) {
      bu[ni] = *(const bf16x8*)&Bu[(wn + ni * 16 + rrow) * LDK + quad * 8];
      bg[ni] = *(const bf16x8*)&Bg[(wn + ni * 16 + rrow) * LDK + quad * 8];
    }
#pragma unroll
    for (int mi = 0; mi < 4; mi++)
#pragma unroll
      for (int ni = 0; ni < 4; ni++) {
        accU[mi][ni] = __builtin_amdgcn_mfma_f32_16x16x32_bf16(af[mi], bu[ni], accU[mi][ni], 0, 0, 0);
        accG[mi][ni] = __builtin_amdgcn_mfma_f32_16x16x32_bf16(af[mi], bg[ni], accG[mi][ni], 0, 0, 0);
      }
    __syncthreads();
  }
#pragma unroll
  for (int mi = 0; mi < 4; mi++)
#pragma unroll
    for (int ni = 0; ni < 4; ni++)
#pragma unroll
      for (int r = 0; r < 4; r++) {
        int row = wm + mi * 16 + quad * 4 + r;
        int col = wn + ni * 16 + rrow;
        float u = accU[mi][ni][r], g = accG[mi][ni][r];
        float sig = 1.0f / (1.0f + __expf(-g));
        hbuf[(size_t)(m0 + row) * I_ + n0 + col] = f2bf(u * g * sig * smask[row]);
      }
}

__global__ __launch_bounds__(256)
void mlp_down_fb(const unsigned short* __restrict__ hbuf,
                 const float* __restrict__ wd, float* __restrict__ out)
{
  __shared__ unsigned short As[TM * LDK];
  __shared__ unsigned short Bs[TN * LDK];
  const int tid = threadIdx.x;
  const int m0 = blockIdx.x * TM, n0 = blockIdx.y * TN;
  const int wave = tid >> 6, lane = tid & 63;
  const int quad = lane >> 4, rrow = lane & 15;
  const int wm = (wave & 1) * 64, wn = (wave >> 1) * 64;

  f32x4 acc[4][4];
  const f32x4 zero = {0.f, 0.f, 0.f, 0.f};
  for (int i = 0; i < 4; i++)
    for (int j = 0; j < 4; j++) acc[i][j] = zero;

  for (int k0 = 0; k0 < I_; k0 += BK) {
#pragma unroll
    for (int s = 0; s < 4; s++) {
      int idx2 = tid + s * 256, row = idx2 >> 3, c4 = (idx2 & 7) * 4;
      us4 av = *(const us4*)&hbuf[(size_t)(m0 + row) * I_ + k0 + c4];
      float4 b = *(const float4*)&wd[(size_t)(n0 + row) * I_ + k0 + c4];
      us4 bv = { f2bf(b.x), f2bf(b.y), f2bf(b.z), f2bf(b.w) };
      *(us4*)&As[row * LDK + c4] = av;
      *(us4*)&Bs[row * LDK + c4] = bv;
    }
    __syncthreads();
    bf16x8 af[4], bf[4];
#pragma unroll
    for (int mi = 0; mi < 4; mi++)
      af[mi] = *(const bf16x8*)&As[(wm + mi * 16 + rrow) * LDK + quad * 8];
#pragma unroll
    for (int ni = 0; ni < 4; ni++)
      bf[ni] = *(const bf16x8*)&Bs[(wn + ni * 16 + rrow) * LDK + quad * 8];
#pragma unroll
    for (int mi = 0; mi < 4; mi++)
#pragma unroll
      for (int ni = 0; ni < 4; ni++)
        acc[mi][ni] = __builtin_amdgcn_mfma_f32_16x16x32_bf16(af[mi], bf[ni], acc[mi][ni], 0, 0, 0);
    __syncthreads();
  }
#pragma unroll
  for (int mi = 0; mi < 4; mi++)
#pragma unroll
    for (int ni = 0; ni < 4; ni++)
#pragma unroll
      for (int r = 0; r < 4; r++) {
        int row = wm + mi * 16 + quad * 4 + r;
        int col = wn + ni * 16 + rrow;
        out[(size_t)(m0 + row) * H_ + n0 + col] = acc[mi][ni][r];
      }
}

// ---------------------------------------------------------------------------
extern "C" void kernel_launch(void* const* d_in, const int* in_sizes, int n_in,
                              void* d_out, int out_size, void* d_ws, size_t ws_size,
                              hipStream_t stream) {
  const float* hs  = (const float*)d_in[0];
  const float* wu  = (const float*)d_in[1];
  const float* wg  = (const float*)d_in[2];
  const float* wd  = (const float*)d_in[3];
  const int*   msk = (const int*)d_in[4];
  float* out = (float*)d_out;

  // workspace layout (bytes)
  const size_t SZ_H  = (size_t)M_ * I_ * 2;   // 90,177,536  compacted h (bf16)
  const size_t SZ_HS = (size_t)M_ * H_ * 2;   // 33,554,432  compacted hs (bf16)
  const size_t SZ_W  = (size_t)I_ * H_ * 2;   // 90,177,536  per weight (bf16)
  const size_t SZ_IDX = (size_t)M_ * 4 + 64;  // idx + cnt
  const size_t NEED = SZ_H + SZ_HS + 3 * SZ_W + SZ_IDX;

  unsigned short* hbuf = (unsigned short*)d_ws;

  if (ws_size >= NEED) {
    char* p = (char*)d_ws;
    unsigned short* hs16c = (unsigned short*)(p + SZ_H);
    unsigned short* wu16  = (unsigned short*)(p + SZ_H + SZ_HS);
    unsigned short* wg16  = (unsigned short*)(p + SZ_H + SZ_HS + SZ_W);
    unsigned short* wd16  = (unsigned short*)(p + SZ_H + SZ_HS + 2 * SZ_W);
    int* idx = (int*)(p + SZ_H + SZ_HS + 3 * SZ_W);
    int* cnt = idx + M_;

    // zero output so masked token rows are exactly 0
    hipMemsetAsync(out, 0, (size_t)out_size * sizeof(float), stream);

    compact_mask<<<1, 256, 0, stream>>>(msk, idx, cnt);
    gather_cvt_hs<<<dim3(M_, H_ / 2048), 256, 0, stream>>>(hs, idx, hs16c);

    const int n8_w = (int)((size_t)I_ * H_ / 8);  // 5,636,096
    cvt_bf16<<<(n8_w + 255) / 256, 256, 0, stream>>>(wu, wu16, n8_w);
    cvt_bf16<<<(n8_w + 255) / 256, 256, 0, stream>>>(wg, wg16, n8_w);
    cvt_bf16<<<(n8_w + 255) / 256, 256, 0, stream>>>(wd, wd16, n8_w);

    dim3 g1(M_ / 128, I_ / 64);   // 32 x 172 (m-tiles beyond active count exit)
    mlp_upgate3<<<g1, dim3(256), 0, stream>>>(hs16c, wu16, wg16, cnt, hbuf);

    dim3 g2(M_ / 128, H_ / 128);  // 32 x 32
    mlp_down3<<<g2, dim3(256), 0, stream>>>(hbuf, wd16, idx, cnt, out);
  } else {
    dim3 g1(M_ / TM, I_ / TN);
    mlp_upgate_fb<<<g1, dim3(256), 0, stream>>>(hs, wu, wg, msk, hbuf);
    dim3 g2(M_ / TM, H_ / TN);
    mlp_down_fb<<<g2, dim3(256), 0, stream>>>(hbuf, wd, out);
  }
}

// Round 3
// 1280.473 us; speedup vs baseline: 1.4938x; 1.0901x over previous
//
#include <hip/hip_runtime.h>
#include <stdint.h>

// Problem dims (fixed by reference)
#define MB_ 2
#define LL_ 2048
#define M_ (MB_*LL_)   // 4096 tokens
#define H_ 4096
#define I_ 11008

typedef __attribute__((ext_vector_type(8))) short bf16x8;
typedef __attribute__((ext_vector_type(4))) float f32x4;
typedef __attribute__((ext_vector_type(4))) unsigned short us4;

__device__ __forceinline__ unsigned short f2bf(float f) {
  union { float f; unsigned int u; } v; v.f = f;
  unsigned int r = v.u + 0x7FFFu + ((v.u >> 16) & 1u);  // RNE
  return (unsigned short)(r >> 16);
}

__device__ __forceinline__ void gl2lds16(const void* g, void* l) {
  __builtin_amdgcn_global_load_lds(
      (const __attribute__((address_space(1))) void*)g,
      (__attribute__((address_space(3))) void*)l, 16, 0, 0);
}

// counted waits + raw barrier. volatile asm w/ memory clobber is the compiler
// fence; s_barrier alone is not a memory fence for the optimizer.
#define WAITV6 asm volatile("s_waitcnt vmcnt(6)" ::: "memory")
#define WAITV0 asm volatile("s_waitcnt vmcnt(0)" ::: "memory")
#define LGKM0  asm volatile("s_waitcnt lgkmcnt(0)" ::: "memory")
#define BAR    __builtin_amdgcn_s_barrier()

// ---------------------------------------------------------------------------
// Compact active token indices. Single block. idx[0..cnt) = active tokens,
// idx[cnt..M_) = 0 (padding so downstream gathers stay in-bounds).
// ---------------------------------------------------------------------------
__global__ __launch_bounds__(256)
void compact_mask(const int* __restrict__ mask, int* __restrict__ idx,
                  int* __restrict__ cnt) {
  __shared__ int lcnt[256];
  __shared__ int loff[256];
  __shared__ int stot;
  const int t = threadIdx.x;
  const int base = t * 16;
  int c = 0;
#pragma unroll
  for (int j = 0; j < 16; j++) c += (mask[base + j] != 0);
  lcnt[t] = c;
  __syncthreads();
  if (t == 0) {
    int s = 0;
    for (int i = 0; i < 256; i++) { loff[i] = s; s += lcnt[i]; }
    stot = s;
    cnt[0] = s;
  }
  __syncthreads();
  int o = loff[t];
#pragma unroll
  for (int j = 0; j < 16; j++)
    if (mask[base + j] != 0) idx[o++] = base + j;
  const int total = stot;
  for (int s = total + t; s < M_; s += 256) idx[s] = 0;
}

// ---------------------------------------------------------------------------
// fp32 -> bf16 bulk conversion (8 elems / thread)
// ---------------------------------------------------------------------------
__global__ __launch_bounds__(256)
void cvt_bf16(const float* __restrict__ src, unsigned short* __restrict__ dst, int n8) {
  int i = blockIdx.x * blockDim.x + threadIdx.x;
  if (i >= n8) return;
  const float4* s = (const float4*)src + (size_t)i * 2;
  float4 a = s[0], b = s[1];
  us4 lo = { f2bf(a.x), f2bf(a.y), f2bf(a.z), f2bf(a.w) };
  us4 hi = { f2bf(b.x), f2bf(b.y), f2bf(b.z), f2bf(b.w) };
  us4* d = (us4*)dst + (size_t)i * 2;
  d[0] = lo; d[1] = hi;
}

// ---------------------------------------------------------------------------
// Gather active hs rows -> compacted bf16 [slot, H].  grid = (M_, H_/2048)
// ---------------------------------------------------------------------------
__global__ __launch_bounds__(256)
void gather_cvt_hs(const float* __restrict__ hs, const int* __restrict__ idx,
                   unsigned short* __restrict__ dst) {
  const int slot = blockIdx.x;
  const int row  = idx[slot];
  const int col  = (blockIdx.y * 256 + threadIdx.x) * 8;
  const float4* s = (const float4*)(hs + (size_t)row * H_ + col);
  float4 a = s[0], b = s[1];
  us4 lo = { f2bf(a.x), f2bf(a.y), f2bf(a.z), f2bf(a.w) };
  us4 hi = { f2bf(b.x), f2bf(b.y), f2bf(b.z), f2bf(b.w) };
  unsigned short* d = dst + (size_t)slot * H_ + col;
  *(us4*)d = lo;
  *(us4*)(d + 4) = hi;
}

// ===========================================================================
// 8-phase-style GEMM1: BM=128, BK=64, 512 thr (8 waves 2Mx4N), 3 LDS buffers,
// counted vmcnt(6), 2 MFMA-phases of 16 per K-tile, T2 XOR-swizzle, T5 prio.
// B-panel = 256 LDS rows: 4 groups of (32 wu rows + 32 wg rows) so each wave
// owns matching up/gate columns. Output tile: 128 x 128 (up & gate fused).
// ===========================================================================
__global__ __launch_bounds__(512, 1)
void mlp_upgate8(const unsigned short* __restrict__ hs16c,
                 const unsigned short* __restrict__ wu16,
                 const unsigned short* __restrict__ wg16,
                 const int* __restrict__ cnt,
                 unsigned short* __restrict__ hbuf)
{
  const int mtiles = (cnt[0] + 127) >> 7;

  // bijective XCD swizzle: nwg = 32*86 = 2752, chunk = 344
  const int lin = blockIdx.y * 32 + blockIdx.x;
  const int sw  = (lin & 7) * 344 + (lin >> 3);
  const int mt  = sw & 31;
  const int nt  = sw >> 5;   // 0..85
  if (mt >= mtiles) return;

  __shared__ unsigned short As[3][128 * 64];   // 48 KB
  __shared__ unsigned short Bs[3][256 * 64];   // 96 KB

  const int tid  = threadIdx.x;
  const int w    = tid >> 6;
  const int lane = tid & 63;
  const int quad = lane >> 4;
  const int rrow = lane & 15;
  const int r7   = rrow & 7;
  const int wr   = w >> 2;   // 0..1: m-half (64 rows)
  const int wc   = w & 3;    // 0..3: B group (32 up + 32 gate cols)
  const int m0   = mt * 128;
  const int n0   = nt * 128;

  // ---- staging sources: linear LDS dest, pre-swizzled global source col ----
  // chunk c: row = c>>3, c16 = c&7; source col16 = c16 ^ (row&7)
  const int cA0 = tid, cA1 = 512 + tid;
  const int rA0 = cA0 >> 3, rA1 = cA1 >> 3;
  const unsigned short* srcA0 =
      hs16c + (size_t)(m0 + rA0) * H_ + (((cA0 & 7) ^ (rA0 & 7)) * 8);
  const unsigned short* srcA1 =
      hs16c + (size_t)(m0 + rA1) * H_ + (((cA1 & 7) ^ (rA1 & 7)) * 8);
  const unsigned short* srcB[4];
#pragma unroll
  for (int j = 0; j < 4; j++) {
    int c = j * 512 + tid;
    int rowb = c >> 3;                 // 0..255
    int g = rowb >> 6, wi = rowb & 63; // group, index within group
    const unsigned short* wb = (wi < 32) ? wu16 : wg16;
    int grow = nt * 128 + g * 32 + (wi & 31);
    srcB[j] = wb + (size_t)grow * H_ + (((c & 7) ^ (rowb & 7)) * 8);
  }

  auto stP1 = [&](int k0, int bb) {
    gl2lds16(srcA0 + k0, &As[bb][cA0 * 8]);
    gl2lds16(srcA1 + k0, &As[bb][cA1 * 8]);
    gl2lds16(srcB[0] + k0, &Bs[bb][(0 * 512 + tid) * 8]);
    gl2lds16(srcB[1] + k0, &Bs[bb][(1 * 512 + tid) * 8]);
  };
  auto stP2 = [&](int k0, int bb) {
    gl2lds16(srcB[2] + k0, &Bs[bb][(2 * 512 + tid) * 8]);
    gl2lds16(srcB[3] + k0, &Bs[bb][(3 * 512 + tid) * 8]);
  };

  // ---- swizzled ds_read offsets (elements) ----
  int aoff[4][2], buoff[2][2], bgoff[2][2];
#pragma unroll
  for (int mi = 0; mi < 4; mi++)
#pragma unroll
    for (int ks = 0; ks < 2; ks++) {
      int row = wr * 64 + mi * 16 + rrow;
      aoff[mi][ks] = row * 64 + (((ks * 4 + quad) ^ r7) * 8);
    }
#pragma unroll
  for (int ni = 0; ni < 2; ni++)
#pragma unroll
    for (int ks = 0; ks < 2; ks++) {
      int rowu = wc * 64 + ni * 16 + rrow;
      int cs   = ((ks * 4 + quad) ^ r7) * 8;
      buoff[ni][ks] = rowu * 64 + cs;
      bgoff[ni][ks] = (rowu + 32) * 64 + cs;
    }

  f32x4 accU[4][2], accG[4][2];
  const f32x4 zero = {0.f, 0.f, 0.f, 0.f};
#pragma unroll
  for (int i = 0; i < 4; i++)
#pragma unroll
    for (int j = 0; j < 2; j++) { accU[i][j] = zero; accG[i][j] = zero; }

  const int NT = H_ / 64;  // 64 K-tiles
  stP1(0, 0); stP2(0, 0);
  stP1(64, 1); stP2(64, 1);
  WAITV6;  // tile 0 landed; tile 1 in flight
  BAR;

  int b = 0, bs = 2;
  for (int t = 0; t < NT; ++t) {
    bf16x8 bu2[2][2], bg2[2][2];
    { // ---- phase 1: m-half 0 ----
      bf16x8 af[2][2];
#pragma unroll
      for (int mm = 0; mm < 2; mm++)
#pragma unroll
        for (int ks = 0; ks < 2; ks++)
          af[mm][ks] = *(const bf16x8*)&As[b][aoff[mm][ks]];
#pragma unroll
      for (int ni = 0; ni < 2; ni++)
#pragma unroll
        for (int ks = 0; ks < 2; ks++) {
          bu2[ni][ks] = *(const bf16x8*)&Bs[b][buoff[ni][ks]];
          bg2[ni][ks] = *(const bf16x8*)&Bs[b][bgoff[ni][ks]];
        }
      if (t + 2 < NT) stP1((t + 2) * 64, bs);
      BAR; LGKM0;
      __builtin_amdgcn_s_setprio(1);
#pragma unroll
      for (int mm = 0; mm < 2; mm++)
#pragma unroll
        for (int ni = 0; ni < 2; ni++)
#pragma unroll
          for (int ks = 0; ks < 2; ks++) {
            accU[mm][ni] = __builtin_amdgcn_mfma_f32_16x16x32_bf16(af[mm][ks], bu2[ni][ks], accU[mm][ni], 0, 0, 0);
            accG[mm][ni] = __builtin_amdgcn_mfma_f32_16x16x32_bf16(af[mm][ks], bg2[ni][ks], accG[mm][ni], 0, 0, 0);
          }
      __builtin_amdgcn_s_setprio(0);
      BAR;
    }
    { // ---- phase 2: m-half 1 (B frags held in regs) ----
      bf16x8 af[2][2];
#pragma unroll
      for (int mm = 0; mm < 2; mm++)
#pragma unroll
        for (int ks = 0; ks < 2; ks++)
          af[mm][ks] = *(const bf16x8*)&As[b][aoff[2 + mm][ks]];
      if (t + 2 < NT) { stP2((t + 2) * 64, bs); WAITV6; } else { WAITV0; }
      BAR; LGKM0;
      __builtin_amdgcn_s_setprio(1);
#pragma unroll
      for (int mm = 0; mm < 2; mm++)
#pragma unroll
        for (int ni = 0; ni < 2; ni++)
#pragma unroll
          for (int ks = 0; ks < 2; ks++) {
            accU[2 + mm][ni] = __builtin_amdgcn_mfma_f32_16x16x32_bf16(af[mm][ks], bu2[ni][ks], accU[2 + mm][ni], 0, 0, 0);
            accG[2 + mm][ni] = __builtin_amdgcn_mfma_f32_16x16x32_bf16(af[mm][ks], bg2[ni][ks], accG[2 + mm][ni], 0, 0, 0);
          }
      __builtin_amdgcn_s_setprio(0);
      BAR;
    }
    b  = (b  + 1 == 3) ? 0 : b  + 1;
    bs = (bs + 1 == 3) ? 0 : bs + 1;
  }

  // epilogue: C/D layout col=lane&15, row=quad*4+reg (verified m89/m91)
#pragma unroll
  for (int mi = 0; mi < 4; mi++)
#pragma unroll
    for (int ni = 0; ni < 2; ni++)
#pragma unroll
      for (int r = 0; r < 4; r++) {
        int row = wr * 64 + mi * 16 + quad * 4 + r;
        int col = wc * 32 + ni * 16 + rrow;
        float u = accU[mi][ni][r];
        float g = accG[mi][ni][r];
        float sig = 1.0f / (1.0f + __expf(-g));
        hbuf[(size_t)(m0 + row) * I_ + n0 + col] = f2bf(u * g * sig);
      }
}

// ===========================================================================
// 8-phase-style GEMM2: BM=128, BN=256, BK=64, same schedule. Scatter rows.
// ===========================================================================
__global__ __launch_bounds__(512, 1)
void mlp_down8(const unsigned short* __restrict__ hbuf,
               const unsigned short* __restrict__ wd16,
               const int* __restrict__ idx, const int* __restrict__ cnt,
               float* __restrict__ out)
{
  const int count  = cnt[0];
  const int mtiles = (count + 127) >> 7;

  // bijective XCD swizzle: nwg = 32*16 = 512, chunk = 64
  const int lin = blockIdx.y * 32 + blockIdx.x;
  const int sw  = (lin & 7) * 64 + (lin >> 3);
  const int mt  = sw & 31;
  const int nt  = sw >> 5;   // 0..15
  if (mt >= mtiles) return;

  __shared__ unsigned short As[3][128 * 64];   // 48 KB
  __shared__ unsigned short Bs[3][256 * 64];   // 96 KB

  const int tid  = threadIdx.x;
  const int w    = tid >> 6;
  const int lane = tid & 63;
  const int quad = lane >> 4;
  const int rrow = lane & 15;
  const int r7   = rrow & 7;
  const int wr   = w >> 2;   // m-half
  const int wc   = w & 3;    // 64-col group
  const int m0   = mt * 128;
  const int n0   = nt * 256;

  const int cA0 = tid, cA1 = 512 + tid;
  const int rA0 = cA0 >> 3, rA1 = cA1 >> 3;
  const unsigned short* srcA0 =
      hbuf + (size_t)(m0 + rA0) * I_ + (((cA0 & 7) ^ (rA0 & 7)) * 8);
  const unsigned short* srcA1 =
      hbuf + (size_t)(m0 + rA1) * I_ + (((cA1 & 7) ^ (rA1 & 7)) * 8);
  const unsigned short* srcB[4];
#pragma unroll
  for (int j = 0; j < 4; j++) {
    int c = j * 512 + tid;
    int rowb = c >> 3;
    srcB[j] = wd16 + (size_t)(n0 + rowb) * I_ + (((c & 7) ^ (rowb & 7)) * 8);
  }

  auto stP1 = [&](int k0, int bb) {
    gl2lds16(srcA0 + k0, &As[bb][cA0 * 8]);
    gl2lds16(srcA1 + k0, &As[bb][cA1 * 8]);
    gl2lds16(srcB[0] + k0, &Bs[bb][(0 * 512 + tid) * 8]);
    gl2lds16(srcB[1] + k0, &Bs[bb][(1 * 512 + tid) * 8]);
  };
  auto stP2 = [&](int k0, int bb) {
    gl2lds16(srcB[2] + k0, &Bs[bb][(2 * 512 + tid) * 8]);
    gl2lds16(srcB[3] + k0, &Bs[bb][(3 * 512 + tid) * 8]);
  };

  int aoff[4][2], boff[4][2];
#pragma unroll
  for (int mi = 0; mi < 4; mi++)
#pragma unroll
    for (int ks = 0; ks < 2; ks++) {
      int row = wr * 64 + mi * 16 + rrow;
      aoff[mi][ks] = row * 64 + (((ks * 4 + quad) ^ r7) * 8);
    }
#pragma unroll
  for (int ni = 0; ni < 4; ni++)
#pragma unroll
    for (int ks = 0; ks < 2; ks++) {
      int row = wc * 64 + ni * 16 + rrow;
      boff[ni][ks] = row * 64 + (((ks * 4 + quad) ^ r7) * 8);
    }

  f32x4 acc[4][4];
  const f32x4 zero = {0.f, 0.f, 0.f, 0.f};
#pragma unroll
  for (int i = 0; i < 4; i++)
#pragma unroll
    for (int j = 0; j < 4; j++) acc[i][j] = zero;

  const int NT = I_ / 64;  // 172 K-tiles
  stP1(0, 0); stP2(0, 0);
  stP1(64, 1); stP2(64, 1);
  WAITV6;
  BAR;

  int b = 0, bs = 2;
  for (int t = 0; t < NT; ++t) {
    bf16x8 bf2[4][2];
    { // phase 1
      bf16x8 af[2][2];
#pragma unroll
      for (int mm = 0; mm < 2; mm++)
#pragma unroll
        for (int ks = 0; ks < 2; ks++)
          af[mm][ks] = *(const bf16x8*)&As[b][aoff[mm][ks]];
#pragma unroll
      for (int ni = 0; ni < 4; ni++)
#pragma unroll
        for (int ks = 0; ks < 2; ks++)
          bf2[ni][ks] = *(const bf16x8*)&Bs[b][boff[ni][ks]];
      if (t + 2 < NT) stP1((t + 2) * 64, bs);
      BAR; LGKM0;
      __builtin_amdgcn_s_setprio(1);
#pragma unroll
      for (int mm = 0; mm < 2; mm++)
#pragma unroll
        for (int ni = 0; ni < 4; ni++)
#pragma unroll
          for (int ks = 0; ks < 2; ks++)
            acc[mm][ni] = __builtin_amdgcn_mfma_f32_16x16x32_bf16(af[mm][ks], bf2[ni][ks], acc[mm][ni], 0, 0, 0);
      __builtin_amdgcn_s_setprio(0);
      BAR;
    }
    { // phase 2
      bf16x8 af[2][2];
#pragma unroll
      for (int mm = 0; mm < 2; mm++)
#pragma unroll
        for (int ks = 0; ks < 2; ks++)
          af[mm][ks] = *(const bf16x8*)&As[b][aoff[2 + mm][ks]];
      if (t + 2 < NT) { stP2((t + 2) * 64, bs); WAITV6; } else { WAITV0; }
      BAR; LGKM0;
      __builtin_amdgcn_s_setprio(1);
#pragma unroll
      for (int mm = 0; mm < 2; mm++)
#pragma unroll
        for (int ni = 0; ni < 4; ni++)
#pragma unroll
          for (int ks = 0; ks < 2; ks++)
            acc[2 + mm][ni] = __builtin_amdgcn_mfma_f32_16x16x32_bf16(af[mm][ks], bf2[ni][ks], acc[2 + mm][ni], 0, 0, 0);
      __builtin_amdgcn_s_setprio(0);
      BAR;
    }
    b  = (b  + 1 == 3) ? 0 : b  + 1;
    bs = (bs + 1 == 3) ? 0 : bs + 1;
  }

#pragma unroll
  for (int mi = 0; mi < 4; mi++)
#pragma unroll
    for (int r = 0; r < 4; r++) {
      int row  = wr * 64 + mi * 16 + quad * 4 + r;
      int slot = m0 + row;
      if (slot < count) {
        int tok = idx[slot];
        float* orow = out + (size_t)tok * H_ + n0;
#pragma unroll
        for (int ni = 0; ni < 4; ni++)
          orow[wc * 64 + ni * 16 + rrow] = acc[mi][ni][r];
      }
    }
}

// ===========================================================================
// Fallback path (round-1 kernels) if ws_size is too small.
// ===========================================================================
#define TM 128
#define TN 128
#define BK 32
#define LDK 40

__global__ __launch_bounds__(256)
void mlp_upgate_fb(const float* __restrict__ hs, const float* __restrict__ wu,
                   const float* __restrict__ wg, const int* __restrict__ mask,
                   unsigned short* __restrict__ hbuf)
{
  __shared__ unsigned short As[TM * LDK];
  __shared__ unsigned short Bu[TN * LDK];
  __shared__ unsigned short Bg[TN * LDK];
  __shared__ float smask[TM];

  const int tid = threadIdx.x;
  const int m0 = blockIdx.x * TM;
  const int n0 = blockIdx.y * TN;
  if (tid < TM) smask[tid] = (float)mask[m0 + tid];
  const int wave = tid >> 6, lane = tid & 63;
  const int quad = lane >> 4, rrow = lane & 15;
  const int wm = (wave & 1) * 64, wn = (wave >> 1) * 64;

  f32x4 accU[4][4], accG[4][4];
  const f32x4 zero = {0.f, 0.f, 0.f, 0.f};
  for (int i = 0; i < 4; i++)
    for (int j = 0; j < 4; j++) { accU[i][j] = zero; accG[i][j] = zero; }

  for (int k0 = 0; k0 < H_; k0 += BK) {
#pragma unroll
    for (int s = 0; s < 4; s++) {
      int idx2 = tid + s * 256, row = idx2 >> 3, c4 = (idx2 & 7) * 4;
      float4 a = *(const float4*)&hs[(size_t)(m0 + row) * H_ + k0 + c4];
      float4 u = *(const float4*)&wu[(size_t)(n0 + row) * H_ + k0 + c4];
      float4 g = *(const float4*)&wg[(size_t)(n0 + row) * H_ + k0 + c4];
      us4 av = { f2bf(a.x), f2bf(a.y), f2bf(a.z), f2bf(a.w) };
      us4 uv = { f2bf(u.x), f2bf(u.y), f2bf(u.z), f2bf(u.w) };
      us4 gv = { f2bf(g.x), f2bf(g.y), f2bf(g.z), f2bf(g.w) };
      *(us4*)&As[row * LDK + c4] = av;
      *(us4*)&Bu[row * LDK + c4] = uv;
      *(us4*)&Bg[row * LDK + c4] = gv;
    }
    __syncthreads();
    bf16x8 af[4], bu[4], bg[4];
#pragma unroll
    for (int mi = 0; mi < 4; mi++)
      af[mi] = *(const bf16x8*)&As[(wm + mi * 16 + rrow) * LDK + quad * 8];
#pragma unroll
    for (int ni = 0; ni < 4; ni++) {
      bu[ni] = *(const bf16x8*)&Bu[(wn + ni * 16 + rrow) * LDK + quad * 8];
      bg[ni] = *(const bf16x8*)&Bg[(wn + ni * 16 + rrow) * LDK + quad * 8];
    }
#pragma unroll
    for (int mi = 0; mi < 4; mi++)
#pragma unroll
      for (int ni = 0; ni < 4; ni++) {
        accU[mi][ni] = __builtin_amdgcn_mfma_f32_16x16x32_bf16(af[mi], bu[ni], accU[mi][ni], 0, 0, 0);
        accG[mi][ni] = __builtin_amdgcn_mfma_f32_16x16x32_bf16(af[mi], bg[ni], accG[mi][ni], 0, 0, 0);
      }
    __syncthreads();
  }
#pragma unroll
  for (int mi = 0; mi < 4; mi++)
#pragma unroll
    for (int ni = 0; ni < 4; ni++)
#pragma unroll
      for (int r = 0; r < 4; r++) {
        int row = wm + mi * 16 + quad * 4 + r;
        int col = wn + ni * 16 + rrow;
        float u = accU[mi][ni][r], g = accG[mi][ni][r];
        float sig = 1.0f / (1.0f + __expf(-g));
        hbuf[(size_t)(m0 + row) * I_ + n0 + col] = f2bf(u * g * sig * smask[row]);
      }
}

__global__ __launch_bounds__(256)
void mlp_down_fb(const unsigned short* __restrict__ hbuf,
                 const float* __restrict__ wd, float* __restrict__ out)
{
  __shared__ unsigned short As[TM * LDK];
  __shared__ unsigned short Bs[TN * LDK];
  const int tid = threadIdx.x;
  const int m0 = blockIdx.x * TM, n0 = blockIdx.y * TN;
  const int wave = tid >> 6, lane = tid & 63;
  const int quad = lane >> 4, rrow = lane & 15;
  const int wm = (wave & 1) * 64, wn = (wave >> 1) * 64;

  f32x4 acc[4][4];
  const f32x4 zero = {0.f, 0.f, 0.f, 0.f};
  for (int i = 0; i < 4; i++)
    for (int j = 0; j < 4; j++) acc[i][j] = zero;

  for (int k0 = 0; k0 < I_; k0 += BK) {
#pragma unroll
    for (int s = 0; s < 4; s++) {
      int idx2 = tid + s * 256, row = idx2 >> 3, c4 = (idx2 & 7) * 4;
      us4 av = *(const us4*)&hbuf[(size_t)(m0 + row) * I_ + k0 + c4];
      float4 b = *(const float4*)&wd[(size_t)(n0 + row) * I_ + k0 + c4];
      us4 bv = { f2bf(b.x), f2bf(b.y), f2bf(b.z), f2bf(b.w) };
      *(us4*)&As[row * LDK + c4] = av;
      *(us4*)&Bs[row * LDK + c4] = bv;
    }
    __syncthreads();
    bf16x8 af[4], bf[4];
#pragma unroll
    for (int mi = 0; mi < 4; mi++)
      af[mi] = *(const bf16x8*)&As[(wm + mi * 16 + rrow) * LDK + quad * 8];
#pragma unroll
    for (int ni = 0; ni < 4; ni++)
      bf[ni] = *(const bf16x8*)&Bs[(wn + ni * 16 + rrow) * LDK + quad * 8];
#pragma unroll
    for (int mi = 0; mi < 4; mi++)
#pragma unroll
      for (int ni = 0; ni < 4; ni++)
        acc[mi][ni] = __builtin_amdgcn_mfma_f32_16x16x32_bf16(af[mi], bf[ni], acc[mi][ni], 0, 0, 0);
    __syncthreads();
  }
#pragma unroll
  for (int mi = 0; mi < 4; mi++)
#pragma unroll
    for (int ni = 0; ni < 4; ni++)
#pragma unroll
      for (int r = 0; r < 4; r++) {
        int row = wm + mi * 16 + quad * 4 + r;
        int col = wn + ni * 16 + rrow;
        out[(size_t)(m0 + row) * H_ + n0 + col] = acc[mi][ni][r];
      }
}

// ---------------------------------------------------------------------------
extern "C" void kernel_launch(void* const* d_in, const int* in_sizes, int n_in,
                              void* d_out, int out_size, void* d_ws, size_t ws_size,
                              hipStream_t stream) {
  const float* hs  = (const float*)d_in[0];
  const float* wu  = (const float*)d_in[1];
  const float* wg  = (const float*)d_in[2];
  const float* wd  = (const float*)d_in[3];
  const int*   msk = (const int*)d_in[4];
  float* out = (float*)d_out;

  // workspace layout (bytes)
  const size_t SZ_H  = (size_t)M_ * I_ * 2;   // 90,177,536  compacted h (bf16)
  const size_t SZ_HS = (size_t)M_ * H_ * 2;   // 33,554,432  compacted hs (bf16)
  const size_t SZ_W  = (size_t)I_ * H_ * 2;   // 90,177,536  per weight (bf16)
  const size_t SZ_IDX = (size_t)M_ * 4 + 64;  // idx + cnt
  const size_t NEED = SZ_H + SZ_HS + 3 * SZ_W + SZ_IDX;

  unsigned short* hbuf = (unsigned short*)d_ws;

  if (ws_size >= NEED) {
    char* p = (char*)d_ws;
    unsigned short* hs16c = (unsigned short*)(p + SZ_H);
    unsigned short* wu16  = (unsigned short*)(p + SZ_H + SZ_HS);
    unsigned short* wg16  = (unsigned short*)(p + SZ_H + SZ_HS + SZ_W);
    unsigned short* wd16  = (unsigned short*)(p + SZ_H + SZ_HS + 2 * SZ_W);
    int* idx = (int*)(p + SZ_H + SZ_HS + 3 * SZ_W);
    int* cnt = idx + M_;

    // zero output so masked token rows are exactly 0
    hipMemsetAsync(out, 0, (size_t)out_size * sizeof(float), stream);

    compact_mask<<<1, 256, 0, stream>>>(msk, idx, cnt);
    gather_cvt_hs<<<dim3(M_, H_ / 2048), 256, 0, stream>>>(hs, idx, hs16c);

    const int n8_w = (int)((size_t)I_ * H_ / 8);  // 5,636,096
    cvt_bf16<<<(n8_w + 255) / 256, 256, 0, stream>>>(wu, wu16, n8_w);
    cvt_bf16<<<(n8_w + 255) / 256, 256, 0, stream>>>(wg, wg16, n8_w);
    cvt_bf16<<<(n8_w + 255) / 256, 256, 0, stream>>>(wd, wd16, n8_w);

    dim3 g1(32, I_ / 128);   // 32 x 86 (m-tiles beyond active count exit)
    mlp_upgate8<<<g1, dim3(512), 0, stream>>>(hs16c, wu16, wg16, cnt, hbuf);

    dim3 g2(32, H_ / 256);   // 32 x 16
    mlp_down8<<<g2, dim3(512), 0, stream>>>(hbuf, wd16, idx, cnt, out);
  } else {
    dim3 g1(M_ / TM, I_ / TN);
    mlp_upgate_fb<<<g1, dim3(256), 0, stream>>>(hs, wu, wg, msk, hbuf);
    dim3 g2(M_ / TM, H_ / TN);
    mlp_down_fb<<<g2, dim3(256), 0, stream>>>(hbuf, wd, out);
  }
}